// Round 8
// baseline (603.286 us; speedup 1.0000x reference)
//
#include <hip/hip_runtime.h>
#include <stdint.h>

namespace {

typedef __attribute__((ext_vector_type(8)))  short short8;   // 8 bf16
typedef __attribute__((ext_vector_type(16))) float f32x16;
typedef __attribute__((ext_vector_type(4)))  float f32x4;

union U4 {
    uint4    q;
    uint32_t u[4];
    uint16_t us[8];
    short8   s8;
};

constexpr float INV_SCALE = 0.08838834764831845f;  // 1/sqrt(128), BOTH attn blocks

// ---- workspace (weight fragment) layout, bytes ----
constexpr size_t WSPROJ = 65536;            // 4c*8kb*2(hi,lo)*1024
constexpr size_t WP1OFF = 6 * WSPROJ;       // Wp1: c=0..7, kb=0..7 -> 131072 B
constexpr size_t WP2OFF = WP1OFF + 131072;  // Wp2 (16x16 frags): kb=0..7 -> 16384 B

// ---- LDS arena (53760 B -> 3 blocks/CU); ALL buffers disjoint: no accumulator
// ever lives across a barrier (R6/R7 lesson: that spills under (256,3)) ----
constexpr int ACT_OFF = 0;      // packed {hi|lo} u32 [32][128], swizzled, 16KB (X->WAV->NF)
constexpr int KB_OFF  = 16384;  // K 1-term RNE bf16 [32][128], swizzled, 8KB
constexpr int VT_OFF  = 24576;  // VT packed u32 [128e][32m], swizzled, 16KB
constexpr int QO_OFF  = 40960;  // Q 1-term RNE bf16 [32][128], swizzled, 8KB
constexpr int S_OFF   = 49152;  // fp32 [32][36dw], 4608B
// H bf16 [32][256] (16KB) aliases [16384,32768) = KB+VT[0:8K], both dead at MLP time

__device__ __forceinline__ int act_addr(int n, int d) {
    return ACT_OFF + ((n * 512 + d * 4) ^ ((n & 31) << 4));
}
__device__ __forceinline__ int pl_addr(int base, int n, int e) {   // bf16 plane [32][128]
    return base + ((n * 256 + e * 2) ^ ((n & 15) << 4));
}
__device__ __forceinline__ int vt_addr(int e, int m) {
    return VT_OFF + ((e * 128 + m * 4) ^ ((e & 7) << 4));
}
__device__ __forceinline__ int s_addr(int n, int m) {
    return S_OFF + n * 144 + m * 4;
}
__device__ __forceinline__ int h_addr(int n, int h) {   // H over dead KB+VT region
    return KB_OFF + ((n * 512 + h * 2) ^ ((n & 15) << 4));
}

__device__ __forceinline__ uint16_t f2bf_rne(float x) {
    uint32_t u = __float_as_uint(x);
    u += 0x7FFFu + ((u >> 16) & 1u);
    return (uint16_t)(u >> 16);
}

// split 8 fp32 -> (hi bf16x8, lo bf16x8); hi = trunc, lo = trunc(x - hi)
__device__ __forceinline__ void split8(float4 a, float4 b, short8& hi, short8& lo) {
    float xs[8] = {a.x, a.y, a.z, a.w, b.x, b.y, b.z, b.w};
    U4 h, l;
#pragma unroll
    for (int p = 0; p < 4; ++p) {
        uint32_t b0 = __float_as_uint(xs[2 * p]);
        uint32_t b1 = __float_as_uint(xs[2 * p + 1]);
        float r0 = xs[2 * p]     - __uint_as_float(b0 & 0xFFFF0000u);
        float r1 = xs[2 * p + 1] - __uint_as_float(b1 & 0xFFFF0000u);
        h.u[p] = __builtin_amdgcn_perm(b1, b0, 0x07060302u);
        l.u[p] = __builtin_amdgcn_perm(__float_as_uint(r1), __float_as_uint(r0), 0x07060302u);
    }
    hi = h.s8; lo = l.s8;
}

// 8 packed dwords {hi16|lo16} -> hi frag / lo frag
__device__ __forceinline__ void unpack8(const uint32_t* d, short8& hi, short8& lo) {
    U4 h, l;
#pragma unroll
    for (int p = 0; p < 4; ++p) {
        h.u[p] = __builtin_amdgcn_perm(d[2 * p + 1], d[2 * p], 0x07060302u);
        l.u[p] = __builtin_amdgcn_perm(d[2 * p + 1], d[2 * p], 0x05040100u);
    }
    hi = h.s8; lo = l.s8;
}

__device__ __forceinline__ uint32_t pack_hilo(float x) {
    uint32_t b = __float_as_uint(x);
    float r = x - __uint_as_float(b & 0xFFFF0000u);
    return __builtin_amdgcn_perm(b, __float_as_uint(r), 0x07060302u);  // [hi(x)|hi(r)]
}

// 32x128 GEMM col-tile c (K=128): acc[n][e] = sum_d A[n][d]*W[e][d], 3-term split.
// A read per-kb from packed-ACT in LDS -> no persistent A registers.
__device__ __forceinline__ f32x16 gemm32(const char* smem, const uint8_t* __restrict__ matbase,
                                         int c, int l) {
    f32x16 acc = {0.f,0.f,0.f,0.f, 0.f,0.f,0.f,0.f, 0.f,0.f,0.f,0.f, 0.f,0.f,0.f,0.f};
    const int n = l & 31, half = l >> 5;
#pragma unroll
    for (int kb = 0; kb < 8; ++kb) {
        const int d0 = kb * 16 + half * 8;
        uint32_t ad[8];
        *(uint4*)&ad[0] = *(const uint4*)(smem + act_addr(n, d0));
        *(uint4*)&ad[4] = *(const uint4*)(smem + act_addr(n, d0 + 4));
        short8 ah, al;
        unpack8(ad, ah, al);
        const uint8_t* p = matbase + (size_t)((c * 8 + kb) * 2) * 1024 + (size_t)l * 16;
        U4 bh, bl;
        bh.q = *(const uint4*)p;
        bl.q = *(const uint4*)(p + 1024);
        acc = __builtin_amdgcn_mfma_f32_32x32x16_bf16(ah, bh.s8, acc, 0, 0, 0);
        acc = __builtin_amdgcn_mfma_f32_32x32x16_bf16(al, bh.s8, acc, 0, 0, 0);
        acc = __builtin_amdgcn_mfma_f32_32x32x16_bf16(ah, bl.s8, acc, 0, 0, 0);
    }
    return acc;
}

// store 32x32 D-tile packed hi/lo into ACT
__device__ __forceinline__ void store_act(char* smem, int c, int l, const f32x16& acc) {
    const int e = c * 32 + (l & 31);
    const int half = l >> 5;
#pragma unroll
    for (int r = 0; r < 16; ++r) {
        int n = (r & 3) + 8 * (r >> 2) + 4 * half;   // verified 32x32 D mapping
        *(uint32_t*)(smem + act_addr(n, e)) = pack_hilo(acc[r]);
    }
}

// store 32x32 D-tile as 1-term RNE bf16 plane (K or Q)
__device__ __forceinline__ void store_plane(char* smem, int base, int c, int l, const f32x16& acc) {
    const int e = c * 32 + (l & 31);
    const int half = l >> 5;
#pragma unroll
    for (int r = 0; r < 16; ++r) {
        int n = (r & 3) + 8 * (r >> 2) + 4 * half;
        *(uint16_t*)(smem + pl_addr(base, n, e)) = f2bf_rne(acc[r]);
    }
}

// -------- pre-pass: convert weights to fragment-ordered split-bf16 in d_ws --------
__global__ void prepack(const float* __restrict__ Wk1, const float* __restrict__ Wq1,
                        const float* __restrict__ Wv1, const float* __restrict__ Wk2,
                        const float* __restrict__ Wq2, const float* __restrict__ Wv2,
                        const float* __restrict__ Wp1, const float* __restrict__ Wp2,
                        uint8_t* __restrict__ wsb) {
    const int bid = blockIdx.x;
    const int l = threadIdx.x;
    float4 fa = make_float4(0.f, 0.f, 0.f, 0.f), fb = fa;
    uint8_t* dst;
    if (bid < 192) {                       // 6 proj matrices, 32x32 B-frags
        int m = bid >> 5, rem = bid & 31, c = rem >> 3, kb = rem & 7;
        const float* W = (m == 0) ? Wk1 : (m == 1) ? Wq1 : (m == 2) ? Wv1
                       : (m == 3) ? Wk2 : (m == 4) ? Wq2 : Wv2;
        int e  = c * 32 + (l & 31);
        int d0 = kb * 16 + (l >> 5) * 8;
        const float* src = W + e * 128 + d0;
        fa = *(const float4*)src;
        fb = *(const float4*)(src + 4);
        dst = wsb + (size_t)m * WSPROJ + (size_t)((c * 8 + kb) * 2) * 1024 + l * 16;
    } else if (bid < 256) {                // Wp1 [256][128]
        int idx = bid - 192, c = idx >> 3, kb = idx & 7;
        int e  = c * 32 + (l & 31);
        int d0 = kb * 16 + (l >> 5) * 8;
        const float* src = Wp1 + e * 128 + d0;
        fa = *(const float4*)src;
        fb = *(const float4*)(src + 4);
        dst = wsb + WP1OFF + (size_t)((c * 8 + kb) * 2) * 1024 + l * 16;
    } else {                               // Wp2 [10][256] -> 16x16 B-frags, cols 10..15 zero
        int kb = bid - 256;
        int a  = l & 15;
        int h0 = kb * 32 + ((l >> 4) & 3) * 8;
        if (a < 10) {
            const float* src = Wp2 + a * 256 + h0;
            fa = *(const float4*)src;
            fb = *(const float4*)(src + 4);
        }
        dst = wsb + WP2OFF + (size_t)(kb * 2) * 1024 + l * 16;
    }
    short8 hi, lo;
    split8(fa, fb, hi, lo);
    *(short8*)dst = hi;
    *(short8*)(dst + 1024) = lo;
}

// -------- main fused kernel: one batch per block, 4 waves, 3 blocks/CU --------
// Every gemm accumulator is stored to its OWN LDS region immediately; no value
// crosses a barrier (R6/R7: barrier-crossing accs spill under (256,3)).
__global__ __launch_bounds__(256, 3)
void fused_net(const float* __restrict__ states, const uint8_t* __restrict__ wsb,
               float* __restrict__ out_policy, float* __restrict__ out_w1,
               float* __restrict__ out_w2) {
    __shared__ __align__(16) char smem[53760];

    const int b    = blockIdx.x;
    const int t    = threadIdx.x;
    const int w    = t >> 6;
    const int l    = t & 63;
    const int l31  = l & 31;
    const int half = l >> 5;
    const int l15  = l & 15;
    const int g4   = (l >> 4) & 3;

    // ---- stage X packed hi/lo into ACT, coalesced ----
    {
        const float* src = states + (size_t)b * 4096;
#pragma unroll
        for (int r = 0; r < 4; ++r) {
            int flat = (t + 256 * r) * 4;
            int n = flat >> 7, d0 = flat & 127;
            float4 v = *(const float4*)(src + flat);
            uint4 p;
            p.x = pack_hilo(v.x); p.y = pack_hilo(v.y);
            p.z = pack_hilo(v.z); p.w = pack_hilo(v.w);
            *(uint4*)(smem + act_addr(n, d0)) = p;
        }
    }
    __syncthreads();

#pragma unroll 1
    for (int blk = 0; blk < 2; ++blk) {
        const uint8_t* wb = wsb + (size_t)(blk * 3) * WSPROJ;

        // ---- projections: each acc stored immediately to its own region ----
        {
            f32x16 acc = gemm32(smem, wb + 0 * WSPROJ, w, l);   // K -> 1-term plane
            store_plane(smem, KB_OFF, w, l, acc);
        }
        {
            f32x16 acc = gemm32(smem, wb + 2 * WSPROJ, w, l);   // V -> packed hi/lo VT
            const int e = w * 32 + l31;
#pragma unroll
            for (int r = 0; r < 16; ++r) {
                int m = (r & 3) + 8 * (r >> 2) + 4 * half;
                *(uint32_t*)(smem + vt_addr(e, m)) = pack_hilo(acc[r]);
            }
        }
        {
            f32x16 acc = gemm32(smem, wb + 1 * WSPROJ, w, l);   // Q -> 1-term plane
            store_plane(smem, QO_OFF, w, l, acc);
        }
        __syncthreads();

        // ---- S = (Q K^T)*inv_scale: 1 MFMA/kb (both operands 1-term planes) ----
        {
            f32x4 s4 = {0.f, 0.f, 0.f, 0.f};
            const int rb = w >> 1, mb = w & 1;
            const int qrow = rb * 16 + l15;
            const int krow = mb * 16 + l15;
#pragma unroll
            for (int kb = 0; kb < 4; ++kb) {
                int e0 = kb * 32 + g4 * 8;
                U4 qh, kh;
                qh.q = *(const uint4*)(smem + pl_addr(QO_OFF, qrow, e0));
                kh.q = *(const uint4*)(smem + pl_addr(KB_OFF, krow, e0));
                s4 = __builtin_amdgcn_mfma_f32_16x16x32_bf16(qh.s8, kh.s8, s4, 0, 0, 0);
            }
#pragma unroll
            for (int r = 0; r < 4; ++r) {
                int n = rb * 16 + g4 * 4 + r;    // verified 16x16 D mapping
                *(float*)(smem + s_addr(n, krow)) = s4[r] * INV_SCALE;
            }
        }
        __syncthreads();

        // ---- softmax over m (wave 0: lane = row | half) ----
        if (t < 64) {
            const int n = l31;
            float4 v0 = *(const float4*)(smem + s_addr(n, half * 16));
            float4 v1 = *(const float4*)(smem + s_addr(n, half * 16 + 4));
            float4 v2 = *(const float4*)(smem + s_addr(n, half * 16 + 8));
            float4 v3 = *(const float4*)(smem + s_addr(n, half * 16 + 12));
            float vv[16] = {v0.x, v0.y, v0.z, v0.w, v1.x, v1.y, v1.z, v1.w,
                            v2.x, v2.y, v2.z, v2.w, v3.x, v3.y, v3.z, v3.w};
            float mx = vv[0];
#pragma unroll
            for (int i = 1; i < 16; ++i) mx = fmaxf(mx, vv[i]);
            mx = fmaxf(mx, __shfl_xor(mx, 32));
            float sum = 0.f;
#pragma unroll
            for (int i = 0; i < 16; ++i) { vv[i] = __expf(vv[i] - mx); sum += vv[i]; }
            sum += __shfl_xor(sum, 32);
            float inv = 1.0f / sum;
#pragma unroll
            for (int i = 0; i < 16; ++i) vv[i] *= inv;
            *(float4*)(smem + s_addr(n, half * 16))      = make_float4(vv[0], vv[1], vv[2], vv[3]);
            *(float4*)(smem + s_addr(n, half * 16 + 4))  = make_float4(vv[4], vv[5], vv[6], vv[7]);
            *(float4*)(smem + s_addr(n, half * 16 + 8))  = make_float4(vv[8], vv[9], vv[10], vv[11]);
            *(float4*)(smem + s_addr(n, half * 16 + 12)) = make_float4(vv[12], vv[13], vv[14], vv[15]);
        }
        __syncthreads();

        // ---- attention-weight output (coalesced) ----
        {
            float* outw = blk ? out_w2 : out_w1;
            int f = t * 4;
            int n = f >> 5, m0 = f & 31;
            float4 o = *(const float4*)(smem + s_addr(n, m0));
            *(float4*)(outw + (size_t)b * 1024 + f) = o;
        }

        // ---- PV: ACT'[n][e] = sum_m P[n][m] V[m][e]; store straight into ACT
        //      (ACT dead since projection barrier; S/VT disjoint -> no wait) ----
        {
            f32x16 pv = {0.f,0.f,0.f,0.f, 0.f,0.f,0.f,0.f, 0.f,0.f,0.f,0.f, 0.f,0.f,0.f,0.f};
            const int e = w * 32 + l31;
#pragma unroll
            for (int kb = 0; kb < 2; ++kb) {
                int m0 = kb * 16 + half * 8;
                float4 fa = *(const float4*)(smem + s_addr(l31, m0));
                float4 fb = *(const float4*)(smem + s_addr(l31, m0 + 4));
                short8 wh, wl;
                split8(fa, fb, wh, wl);
                uint32_t vd[8];
                *(uint4*)&vd[0] = *(const uint4*)(smem + vt_addr(e, m0));
                *(uint4*)&vd[4] = *(const uint4*)(smem + vt_addr(e, m0 + 4));
                short8 vh, vl;
                unpack8(vd, vh, vl);
                pv = __builtin_amdgcn_mfma_f32_32x32x16_bf16(wh, vh, pv, 0, 0, 0);
                pv = __builtin_amdgcn_mfma_f32_32x32x16_bf16(wl, vh, pv, 0, 0, 0);
                pv = __builtin_amdgcn_mfma_f32_32x32x16_bf16(wh, vl, pv, 0, 0, 0);
            }
            store_act(smem, w, l, pv);
        }
        __syncthreads();
    }

    // ---- MLP hidden: H = leaky_relu(NF @ Wp1^T) -> bf16 rne over dead KB/VT ----
#pragma unroll
    for (int rep = 0; rep < 2; ++rep) {
        const int c = w + rep * 4;
        f32x16 acc = gemm32(smem, wsb + WP1OFF, c, l);
        const int hcol = c * 32 + l31;
#pragma unroll
        for (int r = 0; r < 16; ++r) {
            int n = (r & 3) + 8 * (r >> 2) + 4 * half;
            float x = acc[r];
            x = fmaxf(x, 0.01f * x);                      // leaky_relu
            *(uint16_t*)(smem + h_addr(n, hcol)) = f2bf_rne(x);
        }
    }
    __syncthreads();

    // ---- policy logits: 2x 16x16 tiles (waves 0,1), K=256, A=H(1-term), B=Wp2(hi+lo) ----
    if (w < 2) {
        f32x4 acc = {0.f, 0.f, 0.f, 0.f};
        const int n = w * 16 + l15;
#pragma unroll
        for (int kb = 0; kb < 8; ++kb) {
            int h0 = kb * 32 + g4 * 8;
            U4 a;
            a.q = *(const uint4*)(smem + h_addr(n, h0));
            const uint8_t* p = wsb + WP2OFF + (size_t)(kb * 2) * 1024 + (size_t)l * 16;
            U4 bh, bl;
            bh.q = *(const uint4*)p;
            bl.q = *(const uint4*)(p + 1024);
            acc = __builtin_amdgcn_mfma_f32_16x16x32_bf16(a.s8, bh.s8, acc, 0, 0, 0);
            acc = __builtin_amdgcn_mfma_f32_16x16x32_bf16(a.s8, bl.s8, acc, 0, 0, 0);
        }
#pragma unroll
        for (int r = 0; r < 4; ++r) {
            int nn = w * 16 + g4 * 4 + r;
            *(float*)(smem + s_addr(nn, l15)) = acc[r];
        }
    }
    __syncthreads();

    // ---- policy softmax over 10 actions ----
    if (t < 32) {
        float v[10];
#pragma unroll
        for (int a2 = 0; a2 < 10; ++a2) v[a2] = *(const float*)(smem + s_addr(t, a2));
        float mx = v[0];
#pragma unroll
        for (int a2 = 1; a2 < 10; ++a2) mx = fmaxf(mx, v[a2]);
        float sum = 0.f;
#pragma unroll
        for (int a2 = 0; a2 < 10; ++a2) { v[a2] = __expf(v[a2] - mx); sum += v[a2]; }
        float inv = 1.0f / sum;
#pragma unroll
        for (int a2 = 0; a2 < 10; ++a2) *(float*)(smem + s_addr(t, a2)) = v[a2] * inv;
    }
    __syncthreads();

    for (int o = t; o < 320; o += 256) {
        int n = o / 10, a2 = o - n * 10;
        out_policy[(size_t)b * 320 + o] = *(const float*)(smem + s_addr(n, a2));
    }
}

}  // namespace

extern "C" void kernel_launch(void* const* d_in, const int* in_sizes, int n_in,
                              void* d_out, int out_size, void* d_ws, size_t ws_size,
                              hipStream_t stream) {
    const float* states = (const float*)d_in[0];
    const float* Wk1 = (const float*)d_in[1];
    const float* Wq1 = (const float*)d_in[2];
    const float* Wv1 = (const float*)d_in[3];
    const float* Wk2 = (const float*)d_in[4];
    const float* Wq2 = (const float*)d_in[5];
    const float* Wv2 = (const float*)d_in[6];
    const float* Wp1 = (const float*)d_in[7];
    const float* Wp2 = (const float*)d_in[8];

    const int B = in_sizes[0] / 4096;   // 8192

    uint8_t* wsb = (uint8_t*)d_ws;      // needs ~528 KB
    float* out        = (float*)d_out;
    float* out_policy = out;
    float* out_w1     = out_policy + (size_t)B * 320;
    float* out_w2     = out_w1 + (size_t)B * 1024;

    hipLaunchKernelGGL(prepack, dim3(264), dim3(64), 0, stream,
                       Wk1, Wq1, Wv1, Wk2, Wq2, Wv2, Wp1, Wp2, wsb);
    hipLaunchKernelGGL(fused_net, dim3(B), dim3(256), 0, stream,
                       states, wsb, out_policy, out_w1, out_w2);
}

// Round 9
// 278.011 us; speedup vs baseline: 2.1700x; 2.1700x over previous
//
#include <hip/hip_runtime.h>
#include <stdint.h>

namespace {

typedef __attribute__((ext_vector_type(8)))  short short8;   // 8 bf16
typedef __attribute__((ext_vector_type(16))) float f32x16;
typedef __attribute__((ext_vector_type(4)))  float f32x4;

union U4 {
    uint4    q;
    uint32_t u[4];
    uint16_t us[8];
    short8   s8;
};

constexpr float INV_SCALE = 0.08838834764831845f;  // 1/sqrt(128), BOTH attn blocks

// ---- workspace (weight fragment) layout, bytes ----
constexpr size_t WSPROJ = 65536;            // 4c*8kb*2(hi,lo)*1024
constexpr size_t WP1OFF = 6 * WSPROJ;       // Wp1: c=0..7, kb=0..7 -> 131072 B
constexpr size_t WP2OFF = WP1OFF + 131072;  // Wp2 (16x16 frags): kb=0..7 -> 16384 B

// ---- LDS arena (53760 B -> 3 blocks/CU); all buffers disjoint ----
constexpr int ACT_OFF = 0;      // packed {hi|lo} u32 [32][128], swizzled, 16KB (X->WAV->NF)
constexpr int KB_OFF  = 16384;  // K 1-term RNE bf16 [32][128], swizzled, 8KB
constexpr int VT_OFF  = 24576;  // VT packed u32 [128e][32m], swizzled, 16KB
constexpr int QO_OFF  = 40960;  // Q 1-term RNE bf16 [32][128], swizzled, 8KB
constexpr int S_OFF   = 49152;  // fp32 [32][36dw], 4608B
// H bf16 [32][256] (16KB) aliases [16384,32768) = KB+VT[0:8K], both dead at MLP time

__device__ __forceinline__ int act_addr(int n, int d) {
    return ACT_OFF + ((n * 512 + d * 4) ^ ((n & 31) << 4));
}
__device__ __forceinline__ int pl_addr(int base, int n, int e) {   // bf16 plane [32][128]
    return base + ((n * 256 + e * 2) ^ ((n & 15) << 4));
}
__device__ __forceinline__ int vt_addr(int e, int m) {
    return VT_OFF + ((e * 128 + m * 4) ^ ((e & 7) << 4));
}
__device__ __forceinline__ int s_addr(int n, int m) {
    return S_OFF + n * 144 + m * 4;
}
__device__ __forceinline__ int h_addr(int n, int h) {   // H over dead KB+VT region
    return KB_OFF + ((n * 512 + h * 2) ^ ((n & 15) << 4));
}

__device__ __forceinline__ uint16_t f2bf_rne(float x) {
    uint32_t u = __float_as_uint(x);
    u += 0x7FFFu + ((u >> 16) & 1u);
    return (uint16_t)(u >> 16);
}

// split 8 fp32 -> (hi bf16x8, lo bf16x8); hi = trunc, lo = trunc(x - hi)
__device__ __forceinline__ void split8(float4 a, float4 b, short8& hi, short8& lo) {
    float xs[8] = {a.x, a.y, a.z, a.w, b.x, b.y, b.z, b.w};
    U4 h, l;
#pragma unroll
    for (int p = 0; p < 4; ++p) {
        uint32_t b0 = __float_as_uint(xs[2 * p]);
        uint32_t b1 = __float_as_uint(xs[2 * p + 1]);
        float r0 = xs[2 * p]     - __uint_as_float(b0 & 0xFFFF0000u);
        float r1 = xs[2 * p + 1] - __uint_as_float(b1 & 0xFFFF0000u);
        h.u[p] = __builtin_amdgcn_perm(b1, b0, 0x07060302u);
        l.u[p] = __builtin_amdgcn_perm(__float_as_uint(r1), __float_as_uint(r0), 0x07060302u);
    }
    hi = h.s8; lo = l.s8;
}

// 8 packed dwords {hi16|lo16} -> hi frag / lo frag
__device__ __forceinline__ void unpack8(const uint32_t* d, short8& hi, short8& lo) {
    U4 h, l;
#pragma unroll
    for (int p = 0; p < 4; ++p) {
        h.u[p] = __builtin_amdgcn_perm(d[2 * p + 1], d[2 * p], 0x07060302u);
        l.u[p] = __builtin_amdgcn_perm(d[2 * p + 1], d[2 * p], 0x05040100u);
    }
    hi = h.s8; lo = l.s8;
}

__device__ __forceinline__ uint32_t pack_hilo(float x) {
    uint32_t b = __float_as_uint(x);
    float r = x - __uint_as_float(b & 0xFFFF0000u);
    return __builtin_amdgcn_perm(b, __float_as_uint(r), 0x07060302u);  // [hi(x)|hi(r)]
}

// 32x128 GEMM col-tile c (K=128): acc[n][e] = sum_d A[n][d]*W[e][d], 3-term split.
// unroll 2: keeps in-loop live set ~90 regs so one gemm fits under the 170-reg
// (256,3) cap without spilling (R6-R8 lesson).
__device__ __forceinline__ f32x16 gemm32(const char* smem, const uint8_t* __restrict__ matbase,
                                         int c, int l) {
    f32x16 acc = {0.f,0.f,0.f,0.f, 0.f,0.f,0.f,0.f, 0.f,0.f,0.f,0.f, 0.f,0.f,0.f,0.f};
    const int n = l & 31, half = l >> 5;
#pragma unroll 2
    for (int kb = 0; kb < 8; ++kb) {
        const int d0 = kb * 16 + half * 8;
        uint32_t ad[8];
        *(uint4*)&ad[0] = *(const uint4*)(smem + act_addr(n, d0));
        *(uint4*)&ad[4] = *(const uint4*)(smem + act_addr(n, d0 + 4));
        short8 ah, al;
        unpack8(ad, ah, al);
        const uint8_t* p = matbase + (size_t)((c * 8 + kb) * 2) * 1024 + (size_t)l * 16;
        U4 bh, bl;
        bh.q = *(const uint4*)p;
        bl.q = *(const uint4*)(p + 1024);
        acc = __builtin_amdgcn_mfma_f32_32x32x16_bf16(ah, bh.s8, acc, 0, 0, 0);
        acc = __builtin_amdgcn_mfma_f32_32x32x16_bf16(al, bh.s8, acc, 0, 0, 0);
        acc = __builtin_amdgcn_mfma_f32_32x32x16_bf16(ah, bl.s8, acc, 0, 0, 0);
    }
    return acc;
}

// store 32x32 D-tile packed hi/lo into ACT
__device__ __forceinline__ void store_act(char* smem, int c, int l, const f32x16& acc) {
    const int e = c * 32 + (l & 31);
    const int half = l >> 5;
#pragma unroll
    for (int r = 0; r < 16; ++r) {
        int n = (r & 3) + 8 * (r >> 2) + 4 * half;   // verified 32x32 D mapping
        *(uint32_t*)(smem + act_addr(n, e)) = pack_hilo(acc[r]);
    }
}

// store 32x32 D-tile as 1-term RNE bf16 plane (K or Q)
__device__ __forceinline__ void store_plane(char* smem, int base, int c, int l, const f32x16& acc) {
    const int e = c * 32 + (l & 31);
    const int half = l >> 5;
#pragma unroll
    for (int r = 0; r < 16; ++r) {
        int n = (r & 3) + 8 * (r >> 2) + 4 * half;
        *(uint16_t*)(smem + pl_addr(base, n, e)) = f2bf_rne(acc[r]);
    }
}

// -------- pre-pass: convert weights to fragment-ordered split-bf16 in d_ws --------
__global__ void prepack(const float* __restrict__ Wk1, const float* __restrict__ Wq1,
                        const float* __restrict__ Wv1, const float* __restrict__ Wk2,
                        const float* __restrict__ Wq2, const float* __restrict__ Wv2,
                        const float* __restrict__ Wp1, const float* __restrict__ Wp2,
                        uint8_t* __restrict__ wsb) {
    const int bid = blockIdx.x;
    const int l = threadIdx.x;
    float4 fa = make_float4(0.f, 0.f, 0.f, 0.f), fb = fa;
    uint8_t* dst;
    if (bid < 192) {                       // 6 proj matrices, 32x32 B-frags
        int m = bid >> 5, rem = bid & 31, c = rem >> 3, kb = rem & 7;
        const float* W = (m == 0) ? Wk1 : (m == 1) ? Wq1 : (m == 2) ? Wv1
                       : (m == 3) ? Wk2 : (m == 4) ? Wq2 : Wv2;
        int e  = c * 32 + (l & 31);
        int d0 = kb * 16 + (l >> 5) * 8;
        const float* src = W + e * 128 + d0;
        fa = *(const float4*)src;
        fb = *(const float4*)(src + 4);
        dst = wsb + (size_t)m * WSPROJ + (size_t)((c * 8 + kb) * 2) * 1024 + l * 16;
    } else if (bid < 256) {                // Wp1 [256][128]
        int idx = bid - 192, c = idx >> 3, kb = idx & 7;
        int e  = c * 32 + (l & 31);
        int d0 = kb * 16 + (l >> 5) * 8;
        const float* src = Wp1 + e * 128 + d0;
        fa = *(const float4*)src;
        fb = *(const float4*)(src + 4);
        dst = wsb + WP1OFF + (size_t)((c * 8 + kb) * 2) * 1024 + l * 16;
    } else {                               // Wp2 [10][256] -> 16x16 B-frags, cols 10..15 zero
        int kb = bid - 256;
        int a  = l & 15;
        int h0 = kb * 32 + ((l >> 4) & 3) * 8;
        if (a < 10) {
            const float* src = Wp2 + a * 256 + h0;
            fa = *(const float4*)src;
            fb = *(const float4*)(src + 4);
        }
        dst = wsb + WP2OFF + (size_t)(kb * 2) * 1024 + l * 16;
    }
    short8 hi, lo;
    split8(fa, fb, hi, lo);
    *(short8*)dst = hi;
    *(short8*)(dst + 1024) = lo;
}

// -------- main fused kernel: one batch per block, 4 waves, 3 blocks/CU --------
// sched_barrier(0) between gemm phases: stops hipcc from interleaving adjacent
// gemm loops (merged live ranges -> multiple f32x16 accs live -> spill under
// the (256,3) 170-reg cap; R8's 1.2 GB scratch traffic).
__global__ __launch_bounds__(256, 3)
void fused_net(const float* __restrict__ states, const uint8_t* __restrict__ wsb,
               float* __restrict__ out_policy, float* __restrict__ out_w1,
               float* __restrict__ out_w2) {
    __shared__ __align__(16) char smem[53760];

    const int b    = blockIdx.x;
    const int t    = threadIdx.x;
    const int w    = t >> 6;
    const int l    = t & 63;
    const int l31  = l & 31;
    const int half = l >> 5;
    const int l15  = l & 15;
    const int g4   = (l >> 4) & 3;

    // ---- stage X packed hi/lo into ACT, coalesced ----
    {
        const float* src = states + (size_t)b * 4096;
#pragma unroll
        for (int r = 0; r < 4; ++r) {
            int flat = (t + 256 * r) * 4;
            int n = flat >> 7, d0 = flat & 127;
            float4 v = *(const float4*)(src + flat);
            uint4 p;
            p.x = pack_hilo(v.x); p.y = pack_hilo(v.y);
            p.z = pack_hilo(v.z); p.w = pack_hilo(v.w);
            *(uint4*)(smem + act_addr(n, d0)) = p;
        }
    }
    __syncthreads();

#pragma unroll 1
    for (int blk = 0; blk < 2; ++blk) {
        const uint8_t* wb = wsb + (size_t)(blk * 3) * WSPROJ;

        // ---- projections: each acc stored immediately; sched walls between gemms ----
        {
            f32x16 acc = gemm32(smem, wb + 0 * WSPROJ, w, l);   // K -> 1-term plane
            store_plane(smem, KB_OFF, w, l, acc);
        }
        __builtin_amdgcn_sched_barrier(0);
        {
            f32x16 acc = gemm32(smem, wb + 2 * WSPROJ, w, l);   // V -> packed hi/lo VT
            const int e = w * 32 + l31;
#pragma unroll
            for (int r = 0; r < 16; ++r) {
                int m = (r & 3) + 8 * (r >> 2) + 4 * half;
                *(uint32_t*)(smem + vt_addr(e, m)) = pack_hilo(acc[r]);
            }
        }
        __builtin_amdgcn_sched_barrier(0);
        {
            f32x16 acc = gemm32(smem, wb + 1 * WSPROJ, w, l);   // Q -> 1-term plane
            store_plane(smem, QO_OFF, w, l, acc);
        }
        __builtin_amdgcn_sched_barrier(0);
        __syncthreads();

        // ---- S = (Q K^T)*inv_scale: 1 MFMA/kb (both operands 1-term planes) ----
        {
            f32x4 s4 = {0.f, 0.f, 0.f, 0.f};
            const int rb = w >> 1, mb = w & 1;
            const int qrow = rb * 16 + l15;
            const int krow = mb * 16 + l15;
#pragma unroll
            for (int kb = 0; kb < 4; ++kb) {
                int e0 = kb * 32 + g4 * 8;
                U4 qh, kh;
                qh.q = *(const uint4*)(smem + pl_addr(QO_OFF, qrow, e0));
                kh.q = *(const uint4*)(smem + pl_addr(KB_OFF, krow, e0));
                s4 = __builtin_amdgcn_mfma_f32_16x16x32_bf16(qh.s8, kh.s8, s4, 0, 0, 0);
            }
#pragma unroll
            for (int r = 0; r < 4; ++r) {
                int n = rb * 16 + g4 * 4 + r;    // verified 16x16 D mapping
                *(float*)(smem + s_addr(n, krow)) = s4[r] * INV_SCALE;
            }
        }
        __syncthreads();

        // ---- softmax over m (wave 0: lane = row | half) ----
        if (t < 64) {
            const int n = l31;
            float4 v0 = *(const float4*)(smem + s_addr(n, half * 16));
            float4 v1 = *(const float4*)(smem + s_addr(n, half * 16 + 4));
            float4 v2 = *(const float4*)(smem + s_addr(n, half * 16 + 8));
            float4 v3 = *(const float4*)(smem + s_addr(n, half * 16 + 12));
            float vv[16] = {v0.x, v0.y, v0.z, v0.w, v1.x, v1.y, v1.z, v1.w,
                            v2.x, v2.y, v2.z, v2.w, v3.x, v3.y, v3.z, v3.w};
            float mx = vv[0];
#pragma unroll
            for (int i = 1; i < 16; ++i) mx = fmaxf(mx, vv[i]);
            mx = fmaxf(mx, __shfl_xor(mx, 32));
            float sum = 0.f;
#pragma unroll
            for (int i = 0; i < 16; ++i) { vv[i] = __expf(vv[i] - mx); sum += vv[i]; }
            sum += __shfl_xor(sum, 32);
            float inv = 1.0f / sum;
#pragma unroll
            for (int i = 0; i < 16; ++i) vv[i] *= inv;
            *(float4*)(smem + s_addr(n, half * 16))      = make_float4(vv[0], vv[1], vv[2], vv[3]);
            *(float4*)(smem + s_addr(n, half * 16 + 4))  = make_float4(vv[4], vv[5], vv[6], vv[7]);
            *(float4*)(smem + s_addr(n, half * 16 + 8))  = make_float4(vv[8], vv[9], vv[10], vv[11]);
            *(float4*)(smem + s_addr(n, half * 16 + 12)) = make_float4(vv[12], vv[13], vv[14], vv[15]);
        }
        __syncthreads();

        // ---- attention-weight output (coalesced) ----
        {
            float* outw = blk ? out_w2 : out_w1;
            int f = t * 4;
            int n = f >> 5, m0 = f & 31;
            float4 o = *(const float4*)(smem + s_addr(n, m0));
            *(float4*)(outw + (size_t)b * 1024 + f) = o;
        }

        // ---- PV: ACT'[n][e] = sum_m P[n][m] V[m][e]; store straight into ACT ----
        {
            f32x16 pv = {0.f,0.f,0.f,0.f, 0.f,0.f,0.f,0.f, 0.f,0.f,0.f,0.f, 0.f,0.f,0.f,0.f};
            const int e = w * 32 + l31;
#pragma unroll
            for (int kb = 0; kb < 2; ++kb) {
                int m0 = kb * 16 + half * 8;
                float4 fa = *(const float4*)(smem + s_addr(l31, m0));
                float4 fb = *(const float4*)(smem + s_addr(l31, m0 + 4));
                short8 wh, wl;
                split8(fa, fb, wh, wl);
                uint32_t vd[8];
                *(uint4*)&vd[0] = *(const uint4*)(smem + vt_addr(e, m0));
                *(uint4*)&vd[4] = *(const uint4*)(smem + vt_addr(e, m0 + 4));
                short8 vh, vl;
                unpack8(vd, vh, vl);
                pv = __builtin_amdgcn_mfma_f32_32x32x16_bf16(wh, vh, pv, 0, 0, 0);
                pv = __builtin_amdgcn_mfma_f32_32x32x16_bf16(wl, vh, pv, 0, 0, 0);
                pv = __builtin_amdgcn_mfma_f32_32x32x16_bf16(wh, vl, pv, 0, 0, 0);
            }
            store_act(smem, w, l, pv);
        }
        __builtin_amdgcn_sched_barrier(0);
        __syncthreads();
    }

    // ---- MLP hidden: H = leaky_relu(NF @ Wp1^T) -> bf16 rne over dead KB/VT ----
#pragma unroll 1
    for (int rep = 0; rep < 2; ++rep) {
        const int c = w + rep * 4;
        f32x16 acc = gemm32(smem, wsb + WP1OFF, c, l);
        const int hcol = c * 32 + l31;
#pragma unroll
        for (int r = 0; r < 16; ++r) {
            int n = (r & 3) + 8 * (r >> 2) + 4 * half;
            float x = acc[r];
            x = fmaxf(x, 0.01f * x);                      // leaky_relu
            *(uint16_t*)(smem + h_addr(n, hcol)) = f2bf_rne(x);
        }
        __builtin_amdgcn_sched_barrier(0);
    }
    __syncthreads();

    // ---- policy logits: 2x 16x16 tiles (waves 0,1), K=256, A=H(1-term), B=Wp2(hi+lo) ----
    if (w < 2) {
        f32x4 acc = {0.f, 0.f, 0.f, 0.f};
        const int n = w * 16 + l15;
#pragma unroll
        for (int kb = 0; kb < 8; ++kb) {
            int h0 = kb * 32 + g4 * 8;
            U4 a;
            a.q = *(const uint4*)(smem + h_addr(n, h0));
            const uint8_t* p = wsb + WP2OFF + (size_t)(kb * 2) * 1024 + (size_t)l * 16;
            U4 bh, bl;
            bh.q = *(const uint4*)p;
            bl.q = *(const uint4*)(p + 1024);
            acc = __builtin_amdgcn_mfma_f32_16x16x32_bf16(a.s8, bh.s8, acc, 0, 0, 0);
            acc = __builtin_amdgcn_mfma_f32_16x16x32_bf16(a.s8, bl.s8, acc, 0, 0, 0);
        }
#pragma unroll
        for (int r = 0; r < 4; ++r) {
            int nn = w * 16 + g4 * 4 + r;
            *(float*)(smem + s_addr(nn, l15)) = acc[r];
        }
    }
    __syncthreads();

    // ---- policy softmax over 10 actions ----
    if (t < 32) {
        float v[10];
#pragma unroll
        for (int a2 = 0; a2 < 10; ++a2) v[a2] = *(const float*)(smem + s_addr(t, a2));
        float mx = v[0];
#pragma unroll
        for (int a2 = 1; a2 < 10; ++a2) mx = fmaxf(mx, v[a2]);
        float sum = 0.f;
#pragma unroll
        for (int a2 = 0; a2 < 10; ++a2) { v[a2] = __expf(v[a2] - mx); sum += v[a2]; }
        float inv = 1.0f / sum;
#pragma unroll
        for (int a2 = 0; a2 < 10; ++a2) *(float*)(smem + s_addr(t, a2)) = v[a2] * inv;
    }
    __syncthreads();

    for (int o = t; o < 320; o += 256) {
        int n = o / 10, a2 = o - n * 10;
        out_policy[(size_t)b * 320 + o] = *(const float*)(smem + s_addr(n, a2));
    }
}

}  // namespace

extern "C" void kernel_launch(void* const* d_in, const int* in_sizes, int n_in,
                              void* d_out, int out_size, void* d_ws, size_t ws_size,
                              hipStream_t stream) {
    const float* states = (const float*)d_in[0];
    const float* Wk1 = (const float*)d_in[1];
    const float* Wq1 = (const float*)d_in[2];
    const float* Wv1 = (const float*)d_in[3];
    const float* Wk2 = (const float*)d_in[4];
    const float* Wq2 = (const float*)d_in[5];
    const float* Wv2 = (const float*)d_in[6];
    const float* Wp1 = (const float*)d_in[7];
    const float* Wp2 = (const float*)d_in[8];

    const int B = in_sizes[0] / 4096;   // 8192

    uint8_t* wsb = (uint8_t*)d_ws;      // needs ~528 KB
    float* out        = (float*)d_out;
    float* out_policy = out;
    float* out_w1     = out_policy + (size_t)B * 320;
    float* out_w2     = out_w1 + (size_t)B * 1024;

    hipLaunchKernelGGL(prepack, dim3(264), dim3(64), 0, stream,
                       Wk1, Wq1, Wv1, Wk2, Wq2, Wv2, Wp1, Wp2, wsb);
    hipLaunchKernelGGL(fused_net, dim3(B), dim3(256), 0, stream,
                       states, wsb, out_policy, out_w1, out_w2);
}

// Round 10
// 271.634 us; speedup vs baseline: 2.2209x; 1.0235x over previous
//
#include <hip/hip_runtime.h>
#include <stdint.h>

namespace {

typedef __attribute__((ext_vector_type(8)))  short short8;   // 8 bf16
typedef __attribute__((ext_vector_type(16))) float f32x16;
typedef __attribute__((ext_vector_type(4)))  float f32x4;

union U4 {
    uint4    q;
    uint32_t u[4];
    uint16_t us[8];
    short8   s8;
};

constexpr float INV_SCALE = 0.08838834764831845f;  // 1/sqrt(128), BOTH attn blocks

// ---- workspace (weight fragment) layout, bytes ----
constexpr size_t WSPROJ = 65536;            // 4c*8kb*2(hi,lo)*1024
constexpr size_t WP1OFF = 6 * WSPROJ;       // Wp1: c=0..7, kb=0..7 -> 131072 B
constexpr size_t WP2OFF = WP1OFF + 131072;  // Wp2 (16x16 frags): kb=0..7 -> 16384 B

// ---- LDS arena (53760 B -> 3 blocks/CU); all buffers disjoint ----
// ACT as TWO bf16 PLANES (hi, lo) -> A-frag ds_read_b128 is directly the MFMA
// operand, no unpack perms (R9: 512 perms/wave was the top VALU consumer).
constexpr int AH_OFF = 0;       // ACT hi plane bf16 [32][128], swizzled, 8KB
constexpr int AL_OFF = 8192;    // ACT lo plane bf16 [32][128], swizzled, 8KB
constexpr int KB_OFF = 16384;   // K 1-term RNE bf16 [32][128], swizzled, 8KB
constexpr int VT_OFF = 24576;   // VT packed u32 [128e][32m], swizzled, 16KB
constexpr int QO_OFF = 40960;   // Q 1-term RNE bf16 [32][128], swizzled, 8KB
constexpr int S_OFF  = 49152;   // fp32 [32][36dw], 4608B
// H bf16 [32][256] (16KB) aliases [16384,32768) = KB+VT[0:8K], both dead at MLP time

// bf16 plane [32 rows][128 cols]: row=256B, XOR swizzle stays in-row
__device__ __forceinline__ int pl_addr(int base, int n, int e) {
    return base + ((n * 256 + e * 2) ^ ((n & 15) << 4));
}
__device__ __forceinline__ int vt_addr(int e, int m) {
    return VT_OFF + ((e * 128 + m * 4) ^ ((e & 7) << 4));
}
__device__ __forceinline__ int s_addr(int n, int m) {
    return S_OFF + n * 144 + m * 4;
}
__device__ __forceinline__ int h_addr(int n, int h) {   // H over dead KB+VT region
    return KB_OFF + ((n * 512 + h * 2) ^ ((n & 15) << 4));
}

__device__ __forceinline__ uint16_t f2bf_rne(float x) {
    uint32_t u = __float_as_uint(x);
    u += 0x7FFFu + ((u >> 16) & 1u);
    return (uint16_t)(u >> 16);
}

// split 8 fp32 -> (hi bf16x8, lo bf16x8); hi = trunc, lo = trunc(x - hi)
__device__ __forceinline__ void split8(float4 a, float4 b, short8& hi, short8& lo) {
    float xs[8] = {a.x, a.y, a.z, a.w, b.x, b.y, b.z, b.w};
    U4 h, l;
#pragma unroll
    for (int p = 0; p < 4; ++p) {
        uint32_t b0 = __float_as_uint(xs[2 * p]);
        uint32_t b1 = __float_as_uint(xs[2 * p + 1]);
        float r0 = xs[2 * p]     - __uint_as_float(b0 & 0xFFFF0000u);
        float r1 = xs[2 * p + 1] - __uint_as_float(b1 & 0xFFFF0000u);
        h.u[p] = __builtin_amdgcn_perm(b1, b0, 0x07060302u);
        l.u[p] = __builtin_amdgcn_perm(__float_as_uint(r1), __float_as_uint(r0), 0x07060302u);
    }
    hi = h.s8; lo = l.s8;
}

// 8 packed dwords {hi16|lo16} -> hi frag / lo frag (VT only now)
__device__ __forceinline__ void unpack8(const uint32_t* d, short8& hi, short8& lo) {
    U4 h, l;
#pragma unroll
    for (int p = 0; p < 4; ++p) {
        h.u[p] = __builtin_amdgcn_perm(d[2 * p + 1], d[2 * p], 0x07060302u);
        l.u[p] = __builtin_amdgcn_perm(d[2 * p + 1], d[2 * p], 0x05040100u);
    }
    hi = h.s8; lo = l.s8;
}

__device__ __forceinline__ uint32_t pack_hilo(float x) {
    uint32_t b = __float_as_uint(x);
    float r = x - __uint_as_float(b & 0xFFFF0000u);
    return __builtin_amdgcn_perm(b, __float_as_uint(r), 0x07060302u);  // [hi(x)|hi(r)]
}

// 32x128 GEMM col-tile c (K=128): acc[n][e] = sum_d A[n][d]*W[e][d], 3-term split.
// A hi/lo frags are direct b128 plane reads -> ZERO unpack VALU.
__device__ __forceinline__ f32x16 gemm32(const char* smem, const uint8_t* __restrict__ matbase,
                                         int c, int l) {
    f32x16 acc = {0.f,0.f,0.f,0.f, 0.f,0.f,0.f,0.f, 0.f,0.f,0.f,0.f, 0.f,0.f,0.f,0.f};
    const int n = l & 31, half = l >> 5;
#pragma unroll 2
    for (int kb = 0; kb < 8; ++kb) {
        const int d0 = kb * 16 + half * 8;
        U4 ah, al;
        ah.q = *(const uint4*)(smem + pl_addr(AH_OFF, n, d0));
        al.q = *(const uint4*)(smem + pl_addr(AL_OFF, n, d0));
        const uint8_t* p = matbase + (size_t)((c * 8 + kb) * 2) * 1024 + (size_t)l * 16;
        U4 bh, bl;
        bh.q = *(const uint4*)p;
        bl.q = *(const uint4*)(p + 1024);
        acc = __builtin_amdgcn_mfma_f32_32x32x16_bf16(ah.s8, bh.s8, acc, 0, 0, 0);
        acc = __builtin_amdgcn_mfma_f32_32x32x16_bf16(al.s8, bh.s8, acc, 0, 0, 0);
        acc = __builtin_amdgcn_mfma_f32_32x32x16_bf16(ah.s8, bl.s8, acc, 0, 0, 0);
    }
    return acc;
}

// store 32x32 D-tile as hi/lo bf16 planes (ACT)
__device__ __forceinline__ void store_act(char* smem, int c, int l, const f32x16& acc) {
    const int e = c * 32 + (l & 31);
    const int half = l >> 5;
#pragma unroll
    for (int r = 0; r < 16; ++r) {
        int n = (r & 3) + 8 * (r >> 2) + 4 * half;   // verified 32x32 D mapping
        uint32_t bu = __float_as_uint(acc[r]);
        float rr = acc[r] - __uint_as_float(bu & 0xFFFF0000u);
        *(uint16_t*)(smem + pl_addr(AH_OFF, n, e)) = (uint16_t)(bu >> 16);
        *(uint16_t*)(smem + pl_addr(AL_OFF, n, e)) = (uint16_t)(__float_as_uint(rr) >> 16);
    }
}

// store 32x32 D-tile as 1-term RNE bf16 plane (K or Q)
__device__ __forceinline__ void store_plane(char* smem, int base, int c, int l, const f32x16& acc) {
    const int e = c * 32 + (l & 31);
    const int half = l >> 5;
#pragma unroll
    for (int r = 0; r < 16; ++r) {
        int n = (r & 3) + 8 * (r >> 2) + 4 * half;
        *(uint16_t*)(smem + pl_addr(base, n, e)) = f2bf_rne(acc[r]);
    }
}

// -------- pre-pass: convert weights to fragment-ordered split-bf16 in d_ws --------
__global__ void prepack(const float* __restrict__ Wk1, const float* __restrict__ Wq1,
                        const float* __restrict__ Wv1, const float* __restrict__ Wk2,
                        const float* __restrict__ Wq2, const float* __restrict__ Wv2,
                        const float* __restrict__ Wp1, const float* __restrict__ Wp2,
                        uint8_t* __restrict__ wsb) {
    const int bid = blockIdx.x;
    const int l = threadIdx.x;
    float4 fa = make_float4(0.f, 0.f, 0.f, 0.f), fb = fa;
    uint8_t* dst;
    if (bid < 192) {                       // 6 proj matrices, 32x32 B-frags
        int m = bid >> 5, rem = bid & 31, c = rem >> 3, kb = rem & 7;
        const float* W = (m == 0) ? Wk1 : (m == 1) ? Wq1 : (m == 2) ? Wv1
                       : (m == 3) ? Wk2 : (m == 4) ? Wq2 : Wv2;
        int e  = c * 32 + (l & 31);
        int d0 = kb * 16 + (l >> 5) * 8;
        const float* src = W + e * 128 + d0;
        fa = *(const float4*)src;
        fb = *(const float4*)(src + 4);
        dst = wsb + (size_t)m * WSPROJ + (size_t)((c * 8 + kb) * 2) * 1024 + l * 16;
    } else if (bid < 256) {                // Wp1 [256][128]
        int idx = bid - 192, c = idx >> 3, kb = idx & 7;
        int e  = c * 32 + (l & 31);
        int d0 = kb * 16 + (l >> 5) * 8;
        const float* src = Wp1 + e * 128 + d0;
        fa = *(const float4*)src;
        fb = *(const float4*)(src + 4);
        dst = wsb + WP1OFF + (size_t)((c * 8 + kb) * 2) * 1024 + l * 16;
    } else {                               // Wp2 [10][256] -> 16x16 B-frags, cols 10..15 zero
        int kb = bid - 256;
        int a  = l & 15;
        int h0 = kb * 32 + ((l >> 4) & 3) * 8;
        if (a < 10) {
            const float* src = Wp2 + a * 256 + h0;
            fa = *(const float4*)src;
            fb = *(const float4*)(src + 4);
        }
        dst = wsb + WP2OFF + (size_t)(kb * 2) * 1024 + l * 16;
    }
    short8 hi, lo;
    split8(fa, fb, hi, lo);
    *(short8*)dst = hi;
    *(short8*)(dst + 1024) = lo;
}

// -------- main fused kernel: one batch per block, 4 waves, 3 blocks/CU --------
// sched_barrier(0) between gemm phases (R9: stops cross-gemm interleave ->
// no multi-acc live ranges -> no spill under the (256,3) 170-reg cap).
__global__ __launch_bounds__(256, 3)
void fused_net(const float* __restrict__ states, const uint8_t* __restrict__ wsb,
               float* __restrict__ out_policy, float* __restrict__ out_w1,
               float* __restrict__ out_w2) {
    __shared__ __align__(16) char smem[53760];

    const int b    = blockIdx.x;
    const int t    = threadIdx.x;
    const int w    = t >> 6;
    const int l    = t & 63;
    const int l31  = l & 31;
    const int half = l >> 5;
    const int l15  = l & 15;
    const int g4   = (l >> 4) & 3;

    // ---- stage X into hi/lo planes, coalesced ----
    {
        const float* src = states + (size_t)b * 4096;
#pragma unroll
        for (int r = 0; r < 4; ++r) {
            int flat = (t + 256 * r) * 4;
            int n = flat >> 7, d0 = flat & 127;
            float4 v = *(const float4*)(src + flat);
            uint32_t b0 = __float_as_uint(v.x), b1 = __float_as_uint(v.y);
            uint32_t b2 = __float_as_uint(v.z), b3 = __float_as_uint(v.w);
            float r0 = v.x - __uint_as_float(b0 & 0xFFFF0000u);
            float r1 = v.y - __uint_as_float(b1 & 0xFFFF0000u);
            float r2 = v.z - __uint_as_float(b2 & 0xFFFF0000u);
            float r3 = v.w - __uint_as_float(b3 & 0xFFFF0000u);
            uint2 hw, lw;
            hw.x = __builtin_amdgcn_perm(b1, b0, 0x07060302u);
            hw.y = __builtin_amdgcn_perm(b3, b2, 0x07060302u);
            lw.x = __builtin_amdgcn_perm(__float_as_uint(r1), __float_as_uint(r0), 0x07060302u);
            lw.y = __builtin_amdgcn_perm(__float_as_uint(r3), __float_as_uint(r2), 0x07060302u);
            *(uint2*)(smem + pl_addr(AH_OFF, n, d0)) = hw;
            *(uint2*)(smem + pl_addr(AL_OFF, n, d0)) = lw;
        }
    }
    __syncthreads();

#pragma unroll 1
    for (int blk = 0; blk < 2; ++blk) {
        const uint8_t* wb = wsb + (size_t)(blk * 3) * WSPROJ;

        // ---- projections: each acc stored immediately; sched walls between gemms ----
        {
            f32x16 acc = gemm32(smem, wb + 0 * WSPROJ, w, l);   // K -> 1-term plane
            store_plane(smem, KB_OFF, w, l, acc);
        }
        __builtin_amdgcn_sched_barrier(0);
        {
            f32x16 acc = gemm32(smem, wb + 2 * WSPROJ, w, l);   // V -> packed hi/lo VT
            const int e = w * 32 + l31;
#pragma unroll
            for (int r = 0; r < 16; ++r) {
                int m = (r & 3) + 8 * (r >> 2) + 4 * half;
                *(uint32_t*)(smem + vt_addr(e, m)) = pack_hilo(acc[r]);
            }
        }
        __builtin_amdgcn_sched_barrier(0);
        {
            f32x16 acc = gemm32(smem, wb + 1 * WSPROJ, w, l);   // Q -> 1-term plane
            store_plane(smem, QO_OFF, w, l, acc);
        }
        __builtin_amdgcn_sched_barrier(0);
        __syncthreads();

        // ---- S = (Q K^T)*inv_scale: 1 MFMA/kb (both operands 1-term planes) ----
        {
            f32x4 s4 = {0.f, 0.f, 0.f, 0.f};
            const int rb = w >> 1, mb = w & 1;
            const int qrow = rb * 16 + l15;
            const int krow = mb * 16 + l15;
#pragma unroll
            for (int kb = 0; kb < 4; ++kb) {
                int e0 = kb * 32 + g4 * 8;
                U4 qh, kh;
                qh.q = *(const uint4*)(smem + pl_addr(QO_OFF, qrow, e0));
                kh.q = *(const uint4*)(smem + pl_addr(KB_OFF, krow, e0));
                s4 = __builtin_amdgcn_mfma_f32_16x16x32_bf16(qh.s8, kh.s8, s4, 0, 0, 0);
            }
#pragma unroll
            for (int r = 0; r < 4; ++r) {
                int n = rb * 16 + g4 * 4 + r;    // verified 16x16 D mapping
                *(float*)(smem + s_addr(n, krow)) = s4[r] * INV_SCALE;
            }
        }
        __syncthreads();

        // ---- softmax over m (wave 0: lane = row | half) ----
        if (t < 64) {
            const int n = l31;
            float4 v0 = *(const float4*)(smem + s_addr(n, half * 16));
            float4 v1 = *(const float4*)(smem + s_addr(n, half * 16 + 4));
            float4 v2 = *(const float4*)(smem + s_addr(n, half * 16 + 8));
            float4 v3 = *(const float4*)(smem + s_addr(n, half * 16 + 12));
            float vv[16] = {v0.x, v0.y, v0.z, v0.w, v1.x, v1.y, v1.z, v1.w,
                            v2.x, v2.y, v2.z, v2.w, v3.x, v3.y, v3.z, v3.w};
            float mx = vv[0];
#pragma unroll
            for (int i = 1; i < 16; ++i) mx = fmaxf(mx, vv[i]);
            mx = fmaxf(mx, __shfl_xor(mx, 32));
            float sum = 0.f;
#pragma unroll
            for (int i = 0; i < 16; ++i) { vv[i] = __expf(vv[i] - mx); sum += vv[i]; }
            sum += __shfl_xor(sum, 32);
            float inv = 1.0f / sum;
#pragma unroll
            for (int i = 0; i < 16; ++i) vv[i] *= inv;
            *(float4*)(smem + s_addr(n, half * 16))      = make_float4(vv[0], vv[1], vv[2], vv[3]);
            *(float4*)(smem + s_addr(n, half * 16 + 4))  = make_float4(vv[4], vv[5], vv[6], vv[7]);
            *(float4*)(smem + s_addr(n, half * 16 + 8))  = make_float4(vv[8], vv[9], vv[10], vv[11]);
            *(float4*)(smem + s_addr(n, half * 16 + 12)) = make_float4(vv[12], vv[13], vv[14], vv[15]);
        }
        __syncthreads();

        // ---- attention-weight output (coalesced) ----
        {
            float* outw = blk ? out_w2 : out_w1;
            int f = t * 4;
            int n = f >> 5, m0 = f & 31;
            float4 o = *(const float4*)(smem + s_addr(n, m0));
            *(float4*)(outw + (size_t)b * 1024 + f) = o;
        }

        // ---- PV: ACT'[n][e] = sum_m P[n][m] V[m][e]; store into ACT planes ----
        {
            f32x16 pv = {0.f,0.f,0.f,0.f, 0.f,0.f,0.f,0.f, 0.f,0.f,0.f,0.f, 0.f,0.f,0.f,0.f};
            const int e = w * 32 + l31;
#pragma unroll
            for (int kb = 0; kb < 2; ++kb) {
                int m0 = kb * 16 + half * 8;
                float4 fa = *(const float4*)(smem + s_addr(l31, m0));
                float4 fb = *(const float4*)(smem + s_addr(l31, m0 + 4));
                short8 wh, wl;
                split8(fa, fb, wh, wl);
                uint32_t vd[8];
                *(uint4*)&vd[0] = *(const uint4*)(smem + vt_addr(e, m0));
                *(uint4*)&vd[4] = *(const uint4*)(smem + vt_addr(e, m0 + 4));
                short8 vh, vl;
                unpack8(vd, vh, vl);
                pv = __builtin_amdgcn_mfma_f32_32x32x16_bf16(wh, vh, pv, 0, 0, 0);
                pv = __builtin_amdgcn_mfma_f32_32x32x16_bf16(wl, vh, pv, 0, 0, 0);
                pv = __builtin_amdgcn_mfma_f32_32x32x16_bf16(wh, vl, pv, 0, 0, 0);
            }
            store_act(smem, w, l, pv);
        }
        __builtin_amdgcn_sched_barrier(0);
        __syncthreads();
    }

    // ---- MLP hidden: H = leaky_relu(NF @ Wp1^T) -> bf16 rne over dead KB/VT ----
#pragma unroll 1
    for (int rep = 0; rep < 2; ++rep) {
        const int c = w + rep * 4;
        f32x16 acc = gemm32(smem, wsb + WP1OFF, c, l);
        const int hcol = c * 32 + l31;
#pragma unroll
        for (int r = 0; r < 16; ++r) {
            int n = (r & 3) + 8 * (r >> 2) + 4 * half;
            float x = acc[r];
            x = fmaxf(x, 0.01f * x);                      // leaky_relu
            *(uint16_t*)(smem + h_addr(n, hcol)) = f2bf_rne(x);
        }
        __builtin_amdgcn_sched_barrier(0);
    }
    __syncthreads();

    // ---- policy logits: 2x 16x16 tiles (waves 0,1), K=256, A=H(1-term), B=Wp2(hi+lo) ----
    if (w < 2) {
        f32x4 acc = {0.f, 0.f, 0.f, 0.f};
        const int n = w * 16 + l15;
#pragma unroll
        for (int kb = 0; kb < 8; ++kb) {
            int h0 = kb * 32 + g4 * 8;
            U4 a;
            a.q = *(const uint4*)(smem + h_addr(n, h0));
            const uint8_t* p = wsb + WP2OFF + (size_t)(kb * 2) * 1024 + (size_t)l * 16;
            U4 bh, bl;
            bh.q = *(const uint4*)p;
            bl.q = *(const uint4*)(p + 1024);
            acc = __builtin_amdgcn_mfma_f32_16x16x32_bf16(a.s8, bh.s8, acc, 0, 0, 0);
            acc = __builtin_amdgcn_mfma_f32_16x16x32_bf16(a.s8, bl.s8, acc, 0, 0, 0);
        }
#pragma unroll
        for (int r = 0; r < 4; ++r) {
            int nn = w * 16 + g4 * 4 + r;
            *(float*)(smem + s_addr(nn, l15)) = acc[r];
        }
    }
    __syncthreads();

    // ---- policy softmax over 10 actions ----
    if (t < 32) {
        float v[10];
#pragma unroll
        for (int a2 = 0; a2 < 10; ++a2) v[a2] = *(const float*)(smem + s_addr(t, a2));
        float mx = v[0];
#pragma unroll
        for (int a2 = 1; a2 < 10; ++a2) mx = fmaxf(mx, v[a2]);
        float sum = 0.f;
#pragma unroll
        for (int a2 = 0; a2 < 10; ++a2) { v[a2] = __expf(v[a2] - mx); sum += v[a2]; }
        float inv = 1.0f / sum;
#pragma unroll
        for (int a2 = 0; a2 < 10; ++a2) *(float*)(smem + s_addr(t, a2)) = v[a2] * inv;
    }
    __syncthreads();

    for (int o = t; o < 320; o += 256) {
        int n = o / 10, a2 = o - n * 10;
        out_policy[(size_t)b * 320 + o] = *(const float*)(smem + s_addr(n, a2));
    }
}

}  // namespace

extern "C" void kernel_launch(void* const* d_in, const int* in_sizes, int n_in,
                              void* d_out, int out_size, void* d_ws, size_t ws_size,
                              hipStream_t stream) {
    const float* states = (const float*)d_in[0];
    const float* Wk1 = (const float*)d_in[1];
    const float* Wq1 = (const float*)d_in[2];
    const float* Wv1 = (const float*)d_in[3];
    const float* Wk2 = (const float*)d_in[4];
    const float* Wq2 = (const float*)d_in[5];
    const float* Wv2 = (const float*)d_in[6];
    const float* Wp1 = (const float*)d_in[7];
    const float* Wp2 = (const float*)d_in[8];

    const int B = in_sizes[0] / 4096;   // 8192

    uint8_t* wsb = (uint8_t*)d_ws;      // needs ~528 KB
    float* out        = (float*)d_out;
    float* out_policy = out;
    float* out_w1     = out_policy + (size_t)B * 320;
    float* out_w2     = out_w1 + (size_t)B * 1024;

    hipLaunchKernelGGL(prepack, dim3(264), dim3(64), 0, stream,
                       Wk1, Wq1, Wv1, Wk2, Wq2, Wv2, Wp1, Wp2, wsb);
    hipLaunchKernelGGL(fused_net, dim3(B), dim3(256), 0, stream,
                       states, wsb, out_policy, out_w1, out_w2);
}

// Round 11
// 254.221 us; speedup vs baseline: 2.3731x; 1.0685x over previous
//
#include <hip/hip_runtime.h>
#include <stdint.h>

namespace {

typedef __attribute__((ext_vector_type(8)))  short short8;   // 8 bf16
typedef __attribute__((ext_vector_type(16))) float f32x16;
typedef __attribute__((ext_vector_type(4)))  float f32x4;

union U4 {
    uint4    q;
    uint32_t u[4];
    uint16_t us[8];
    short8   s8;
};

constexpr float INV_SCALE = 0.08838834764831845f;  // 1/sqrt(128), BOTH attn blocks

// ---- workspace (weight fragment) layout, bytes (prepack UNCHANGED from R10) ----
constexpr size_t WSPROJ = 65536;            // 4c*8kb*2(hi,lo)*1024
constexpr size_t WP1OFF = 6 * WSPROJ;       // Wp1: c=0..7, kb=0..7 -> 131072 B
constexpr size_t WP2OFF = WP1OFF + 131072;  // Wp2 (16x16 frags): kb=0..7 -> 16384 B

// ---- LDS arena: 65536 B, TWO batches row-stacked (64 rows) -> 2 blocks/CU ----
// Weight L2 traffic halves: each B-fragment feeds 2 row-tiles (R10 analysis:
// 4.6 GB L2 weight re-reads ~= 132 us was ~half the runtime).
constexpr int AH_OFF = 0;       // X/WAV/NF hi plane bf16 [64][128], swizzled, 16KB
constexpr int AL_OFF = 16384;   // X/WAV/NF lo plane 16KB; Q plane ALIASES here (X-lo dead post-proj)
constexpr int KB_OFF = 32768;   // K plane bf16 [64][128] 16KB; S fp32 [64][36dw] aliases post-S-read
constexpr int VT_OFF = 49152;   // V 1-term RNE plane [128 e][64 m] bf16, swizzled, 16KB
// H bf16 [64][256] (32KB) aliases KB+VT at MLP time; policy logits alias AH.

__device__ __forceinline__ int pl_addr(int base, int n, int e) {   // bf16 plane [64][128]
    return base + ((n * 256 + e * 2) ^ ((n & 15) << 4));
}
__device__ __forceinline__ int vt_addr(int e, int m) {             // bf16 [128][64]
    return VT_OFF + ((e * 128 + m * 2) ^ ((e & 7) << 4));
}
__device__ __forceinline__ int s_addr(int n, int m) {              // fp32 [64][36dw], over KB
    return KB_OFF + n * 144 + m * 4;
}
__device__ __forceinline__ int h_addr(int n, int h) {              // bf16 [64][256], over KB+VT
    return KB_OFF + ((n * 512 + h * 2) ^ ((n & 15) << 4));
}
__device__ __forceinline__ int ps_addr(int n, int a) {             // fp32 [64][36dw], over AH
    return AH_OFF + n * 144 + a * 4;
}

__device__ __forceinline__ uint16_t f2bf_rne(float x) {
    uint32_t u = __float_as_uint(x);
    u += 0x7FFFu + ((u >> 16) & 1u);
    return (uint16_t)(u >> 16);
}

// split 8 fp32 -> (hi bf16x8, lo bf16x8); hi = trunc, lo = trunc(x - hi)
__device__ __forceinline__ void split8(float4 a, float4 b, short8& hi, short8& lo) {
    float xs[8] = {a.x, a.y, a.z, a.w, b.x, b.y, b.z, b.w};
    U4 h, l;
#pragma unroll
    for (int p = 0; p < 4; ++p) {
        uint32_t b0 = __float_as_uint(xs[2 * p]);
        uint32_t b1 = __float_as_uint(xs[2 * p + 1]);
        float r0 = xs[2 * p]     - __uint_as_float(b0 & 0xFFFF0000u);
        float r1 = xs[2 * p + 1] - __uint_as_float(b1 & 0xFFFF0000u);
        h.u[p] = __builtin_amdgcn_perm(b1, b0, 0x07060302u);
        l.u[p] = __builtin_amdgcn_perm(__float_as_uint(r1), __float_as_uint(r0), 0x07060302u);
    }
    hi = h.s8; lo = l.s8;
}

// 64-row GEMM col-tile c (K=128): OUT[n][e]=sum_d A[n][d]*W[e][d], 3-term split.
// Two row-tiles (acc0: rows 0-31, acc1: rows 32-63) share every B-load.
__device__ __forceinline__ void gemm64(const char* smem, const uint8_t* __restrict__ matbase,
                                       int c, int l, f32x16& acc0, f32x16& acc1) {
    f32x16 z = {0.f,0.f,0.f,0.f, 0.f,0.f,0.f,0.f, 0.f,0.f,0.f,0.f, 0.f,0.f,0.f,0.f};
    acc0 = z; acc1 = z;
    const int n = l & 31, half = l >> 5;
#pragma unroll 2
    for (int kb = 0; kb < 8; ++kb) {
        const int d0 = kb * 16 + half * 8;
        U4 ah0, al0, ah1, al1;
        ah0.q = *(const uint4*)(smem + pl_addr(AH_OFF, n, d0));
        al0.q = *(const uint4*)(smem + pl_addr(AL_OFF, n, d0));
        ah1.q = *(const uint4*)(smem + pl_addr(AH_OFF, n + 32, d0));
        al1.q = *(const uint4*)(smem + pl_addr(AL_OFF, n + 32, d0));
        const uint8_t* p = matbase + (size_t)((c * 8 + kb) * 2) * 1024 + (size_t)l * 16;
        U4 bh, bl;
        bh.q = *(const uint4*)p;
        bl.q = *(const uint4*)(p + 1024);
        acc0 = __builtin_amdgcn_mfma_f32_32x32x16_bf16(ah0.s8, bh.s8, acc0, 0, 0, 0);
        acc0 = __builtin_amdgcn_mfma_f32_32x32x16_bf16(al0.s8, bh.s8, acc0, 0, 0, 0);
        acc0 = __builtin_amdgcn_mfma_f32_32x32x16_bf16(ah0.s8, bl.s8, acc0, 0, 0, 0);
        acc1 = __builtin_amdgcn_mfma_f32_32x32x16_bf16(ah1.s8, bh.s8, acc1, 0, 0, 0);
        acc1 = __builtin_amdgcn_mfma_f32_32x32x16_bf16(al1.s8, bh.s8, acc1, 0, 0, 0);
        acc1 = __builtin_amdgcn_mfma_f32_32x32x16_bf16(ah1.s8, bl.s8, acc1, 0, 0, 0);
    }
}

// store 64x32 D-tiles as 1-term RNE bf16 plane (K or Q)
__device__ __forceinline__ void store_plane64(char* smem, int base, int c, int l,
                                              const f32x16& a0, const f32x16& a1) {
    const int e = c * 32 + (l & 31);
    const int half = l >> 5;
#pragma unroll
    for (int r = 0; r < 16; ++r) {
        int n = (r & 3) + 8 * (r >> 2) + 4 * half;   // verified 32x32 D mapping
        *(uint16_t*)(smem + pl_addr(base, n, e))      = f2bf_rne(a0[r]);
        *(uint16_t*)(smem + pl_addr(base, n + 32, e)) = f2bf_rne(a1[r]);
    }
}

// store one 32x32 D-tile (batch bq) as hi/lo trunc-split ACT planes
__device__ __forceinline__ void store_act64(char* smem, int bq, int c, int l, const f32x16& a) {
    const int e = c * 32 + (l & 31);
    const int half = l >> 5;
#pragma unroll
    for (int r = 0; r < 16; ++r) {
        int n = bq * 32 + (r & 3) + 8 * (r >> 2) + 4 * half;
        uint32_t bu = __float_as_uint(a[r]);
        float rr = a[r] - __uint_as_float(bu & 0xFFFF0000u);
        *(uint16_t*)(smem + pl_addr(AH_OFF, n, e)) = (uint16_t)(bu >> 16);
        *(uint16_t*)(smem + pl_addr(AL_OFF, n, e)) = (uint16_t)(__float_as_uint(rr) >> 16);
    }
}

// -------- pre-pass: convert weights to fragment-ordered split-bf16 in d_ws --------
__global__ void prepack(const float* __restrict__ Wk1, const float* __restrict__ Wq1,
                        const float* __restrict__ Wv1, const float* __restrict__ Wk2,
                        const float* __restrict__ Wq2, const float* __restrict__ Wv2,
                        const float* __restrict__ Wp1, const float* __restrict__ Wp2,
                        uint8_t* __restrict__ wsb) {
    const int bid = blockIdx.x;
    const int l = threadIdx.x;
    float4 fa = make_float4(0.f, 0.f, 0.f, 0.f), fb = fa;
    uint8_t* dst;
    if (bid < 192) {                       // 6 proj matrices, 32x32 B-frags
        int m = bid >> 5, rem = bid & 31, c = rem >> 3, kb = rem & 7;
        const float* W = (m == 0) ? Wk1 : (m == 1) ? Wq1 : (m == 2) ? Wv1
                       : (m == 3) ? Wk2 : (m == 4) ? Wq2 : Wv2;
        int e  = c * 32 + (l & 31);
        int d0 = kb * 16 + (l >> 5) * 8;
        const float* src = W + e * 128 + d0;
        fa = *(const float4*)src;
        fb = *(const float4*)(src + 4);
        dst = wsb + (size_t)m * WSPROJ + (size_t)((c * 8 + kb) * 2) * 1024 + l * 16;
    } else if (bid < 256) {                // Wp1 [256][128]
        int idx = bid - 192, c = idx >> 3, kb = idx & 7;
        int e  = c * 32 + (l & 31);
        int d0 = kb * 16 + (l >> 5) * 8;
        const float* src = Wp1 + e * 128 + d0;
        fa = *(const float4*)src;
        fb = *(const float4*)(src + 4);
        dst = wsb + WP1OFF + (size_t)((c * 8 + kb) * 2) * 1024 + l * 16;
    } else {                               // Wp2 [10][256] -> 16x16 B-frags, cols 10..15 zero
        int kb = bid - 256;
        int a  = l & 15;
        int h0 = kb * 32 + ((l >> 4) & 3) * 8;
        if (a < 10) {
            const float* src = Wp2 + a * 256 + h0;
            fa = *(const float4*)src;
            fb = *(const float4*)(src + 4);
        }
        dst = wsb + WP2OFF + (size_t)(kb * 2) * 1024 + l * 16;
    }
    short8 hi, lo;
    split8(fa, fb, hi, lo);
    *(short8*)dst = hi;
    *(short8*)(dst + 1024) = lo;
}

// -------- main fused kernel: TWO batches per block (row-stacked), 4 waves --------
// (256,2): 256-reg budget -> barrier-crossing Q-acc is safe (R6-R8 spills were
// artifacts of the (256,3) 170-reg cap). Occupancy is LDS-capped at 2 blocks/CU.
__global__ __launch_bounds__(256, 2)
void fused_net(const float* __restrict__ states, const uint8_t* __restrict__ wsb,
               float* __restrict__ out_policy, float* __restrict__ out_w1,
               float* __restrict__ out_w2) {
    __shared__ __align__(16) char smem[65536];

    const int b2   = blockIdx.x;       // batch pair index
    const int t    = threadIdx.x;
    const int w    = t >> 6;
    const int l    = t & 63;
    const int l31  = l & 31;
    const int half = l >> 5;
    const int l15  = l & 15;
    const int g4   = (l >> 4) & 3;

    // ---- stage 2 batches of X into hi/lo planes, coalesced ----
    {
        const float* src = states + (size_t)b2 * 8192;
#pragma unroll
        for (int r = 0; r < 8; ++r) {
            int flat = (t + 256 * r) * 4;
            int n = flat >> 7, d0 = flat & 127;    // n 0..63 (stacked rows)
            float4 v = *(const float4*)(src + flat);
            uint32_t b0 = __float_as_uint(v.x), b1 = __float_as_uint(v.y);
            uint32_t b2u = __float_as_uint(v.z), b3 = __float_as_uint(v.w);
            float r0 = v.x - __uint_as_float(b0 & 0xFFFF0000u);
            float r1 = v.y - __uint_as_float(b1 & 0xFFFF0000u);
            float r2 = v.z - __uint_as_float(b2u & 0xFFFF0000u);
            float r3 = v.w - __uint_as_float(b3 & 0xFFFF0000u);
            uint2 hw, lw;
            hw.x = __builtin_amdgcn_perm(b1, b0, 0x07060302u);
            hw.y = __builtin_amdgcn_perm(b3, b2u, 0x07060302u);
            lw.x = __builtin_amdgcn_perm(__float_as_uint(r1), __float_as_uint(r0), 0x07060302u);
            lw.y = __builtin_amdgcn_perm(__float_as_uint(r3), __float_as_uint(r2), 0x07060302u);
            *(uint2*)(smem + pl_addr(AH_OFF, n, d0)) = hw;
            *(uint2*)(smem + pl_addr(AL_OFF, n, d0)) = lw;
        }
    }
    __syncthreads();

#pragma unroll 1
    for (int blk = 0; blk < 2; ++blk) {
        const uint8_t* wb = wsb + (size_t)(blk * 3) * WSPROJ;

        // ---- projections (64-row): K, V stored immediately; Q acc held over ONE barrier ----
        {
            f32x16 a0, a1;
            gemm64(smem, wb + 0 * WSPROJ, w, l, a0, a1);        // K
            store_plane64(smem, KB_OFF, w, l, a0, a1);
        }
        __builtin_amdgcn_sched_barrier(0);
        {
            f32x16 a0, a1;
            gemm64(smem, wb + 2 * WSPROJ, w, l, a0, a1);        // V -> 1-term plane
            const int e = w * 32 + l31;
#pragma unroll
            for (int r = 0; r < 16; ++r) {
                int m = (r & 3) + 8 * (r >> 2) + 4 * half;
                *(uint16_t*)(smem + vt_addr(e, m))      = f2bf_rne(a0[r]);
                *(uint16_t*)(smem + vt_addr(e, m + 32)) = f2bf_rne(a1[r]);
            }
        }
        __builtin_amdgcn_sched_barrier(0);
        {
            f32x16 q0, q1;
            gemm64(smem, wb + 1 * WSPROJ, w, l, q0, q1);        // Q
            __syncthreads();                       // all X reads done; K/V visible
            store_plane64(smem, AL_OFF, w, l, q0, q1);          // Q into dead X-lo
        }
        __builtin_amdgcn_sched_barrier(0);
        __syncthreads();                            // Q visible

        // ---- S = (Q K^T)*inv_scale: 8x 16x16 tiles; wave w -> batch w>>1, row-blk w&1 ----
        {
            const int bq = w >> 1, rb = w & 1;
            float sreg[8];
#pragma unroll
            for (int mb = 0; mb < 2; ++mb) {
                f32x4 s4 = {0.f, 0.f, 0.f, 0.f};
                const int qrow = bq * 32 + rb * 16 + l15;
                const int krow = bq * 32 + mb * 16 + l15;
#pragma unroll
                for (int kb = 0; kb < 4; ++kb) {
                    int e0 = kb * 32 + g4 * 8;
                    U4 qh, kh;
                    qh.q = *(const uint4*)(smem + pl_addr(AL_OFF, qrow, e0));
                    kh.q = *(const uint4*)(smem + pl_addr(KB_OFF, krow, e0));
                    s4 = __builtin_amdgcn_mfma_f32_16x16x32_bf16(qh.s8, kh.s8, s4, 0, 0, 0);
                }
#pragma unroll
                for (int r = 0; r < 4; ++r) sreg[mb * 4 + r] = s4[r];
            }
            __syncthreads();                        // all K/Q reads done (S aliases KB)
#pragma unroll
            for (int mb = 0; mb < 2; ++mb)
#pragma unroll
                for (int r = 0; r < 4; ++r) {
                    int n = bq * 32 + rb * 16 + g4 * 4 + r;    // verified 16x16 D mapping
                    *(float*)(smem + s_addr(n, mb * 16 + l15)) = sreg[mb * 4 + r] * INV_SCALE;
                }
        }
        __syncthreads();

        // ---- softmax over m: wave 0 -> batch 0 rows, wave 1 -> batch 1 rows ----
        if (t < 128) {
            const int n = w * 32 + l31;
            float4 v0 = *(const float4*)(smem + s_addr(n, half * 16));
            float4 v1 = *(const float4*)(smem + s_addr(n, half * 16 + 4));
            float4 v2 = *(const float4*)(smem + s_addr(n, half * 16 + 8));
            float4 v3 = *(const float4*)(smem + s_addr(n, half * 16 + 12));
            float vv[16] = {v0.x, v0.y, v0.z, v0.w, v1.x, v1.y, v1.z, v1.w,
                            v2.x, v2.y, v2.z, v2.w, v3.x, v3.y, v3.z, v3.w};
            float mx = vv[0];
#pragma unroll
            for (int i = 1; i < 16; ++i) mx = fmaxf(mx, vv[i]);
            mx = fmaxf(mx, __shfl_xor(mx, 32));
            float sum = 0.f;
#pragma unroll
            for (int i = 0; i < 16; ++i) { vv[i] = __expf(vv[i] - mx); sum += vv[i]; }
            sum += __shfl_xor(sum, 32);
            float inv = 1.0f / sum;
#pragma unroll
            for (int i = 0; i < 16; ++i) vv[i] *= inv;
            *(float4*)(smem + s_addr(n, half * 16))      = make_float4(vv[0], vv[1], vv[2], vv[3]);
            *(float4*)(smem + s_addr(n, half * 16 + 4))  = make_float4(vv[4], vv[5], vv[6], vv[7]);
            *(float4*)(smem + s_addr(n, half * 16 + 8))  = make_float4(vv[8], vv[9], vv[10], vv[11]);
            *(float4*)(smem + s_addr(n, half * 16 + 12)) = make_float4(vv[12], vv[13], vv[14], vv[15]);
        }
        __syncthreads();

        // ---- attention-weight output for both batches (coalesced) ----
        {
            float* outw = blk ? out_w2 : out_w1;
#pragma unroll
            for (int it = 0; it < 2; ++it) {
                int f = t * 4 + it * 1024;          // 0..2047
                int n = f >> 5, m0 = f & 31;
                float4 o = *(const float4*)(smem + s_addr(n, m0));
                *(float4*)(outw + (size_t)b2 * 2048 + f) = o;
            }
        }

        // ---- PV per batch: ACT'[n][e] = sum_m P[n][m] V[m][e]; P 2-term x V 1-term ----
#pragma unroll
        for (int bq = 0; bq < 2; ++bq) {
            f32x16 pv = {0.f,0.f,0.f,0.f, 0.f,0.f,0.f,0.f, 0.f,0.f,0.f,0.f, 0.f,0.f,0.f,0.f};
            const int e = w * 32 + l31;
#pragma unroll
            for (int kb = 0; kb < 2; ++kb) {
                int m0 = kb * 16 + half * 8;
                float4 fa = *(const float4*)(smem + s_addr(bq * 32 + l31, m0));
                float4 fb = *(const float4*)(smem + s_addr(bq * 32 + l31, m0 + 4));
                short8 wh, wl;
                split8(fa, fb, wh, wl);
                U4 vh;
                vh.q = *(const uint4*)(smem + vt_addr(e, bq * 32 + m0));
                pv = __builtin_amdgcn_mfma_f32_32x32x16_bf16(wh, vh.s8, pv, 0, 0, 0);
                pv = __builtin_amdgcn_mfma_f32_32x32x16_bf16(wl, vh.s8, pv, 0, 0, 0);
            }
            store_act64(smem, bq, w, l, pv);
        }
        __builtin_amdgcn_sched_barrier(0);
        __syncthreads();
    }

    // ---- MLP hidden (64-row): H = leaky_relu(NF @ Wp1^T) -> bf16 over dead KB+VT ----
#pragma unroll 1
    for (int rep = 0; rep < 2; ++rep) {
        const int c = w + rep * 4;
        f32x16 h0_, h1_;
        gemm64(smem, wsb + WP1OFF, c, l, h0_, h1_);
        const int hcol = c * 32 + l31;
#pragma unroll
        for (int r = 0; r < 16; ++r) {
            int n = (r & 3) + 8 * (r >> 2) + 4 * half;
            float x0 = h0_[r]; x0 = fmaxf(x0, 0.01f * x0);
            float x1 = h1_[r]; x1 = fmaxf(x1, 0.01f * x1);
            *(uint16_t*)(smem + h_addr(n, hcol))      = f2bf_rne(x0);
            *(uint16_t*)(smem + h_addr(n + 32, hcol)) = f2bf_rne(x1);
        }
        __builtin_amdgcn_sched_barrier(0);
    }
    __syncthreads();

    // ---- policy logits: 4x 16x16 tiles (ALL waves), K=256; logits -> dead AH ----
    {
        f32x4 acc = {0.f, 0.f, 0.f, 0.f};
        const int n = w * 16 + l15;                 // rows 0..63
#pragma unroll
        for (int kb = 0; kb < 8; ++kb) {
            int h0 = kb * 32 + g4 * 8;
            U4 a;
            a.q = *(const uint4*)(smem + h_addr(n, h0));
            const uint8_t* p = wsb + WP2OFF + (size_t)(kb * 2) * 1024 + (size_t)l * 16;
            U4 bh, bl;
            bh.q = *(const uint4*)p;
            bl.q = *(const uint4*)(p + 1024);
            acc = __builtin_amdgcn_mfma_f32_16x16x32_bf16(a.s8, bh.s8, acc, 0, 0, 0);
            acc = __builtin_amdgcn_mfma_f32_16x16x32_bf16(a.s8, bl.s8, acc, 0, 0, 0);
        }
#pragma unroll
        for (int r = 0; r < 4; ++r) {
            int nn = w * 16 + g4 * 4 + r;
            *(float*)(smem + ps_addr(nn, l15)) = acc[r];
        }
    }
    __syncthreads();

    // ---- policy softmax over 10 actions (64 rows, 1 row/lane in wave 0) ----
    if (t < 64) {
        float v[10];
#pragma unroll
        for (int a2 = 0; a2 < 10; ++a2) v[a2] = *(const float*)(smem + ps_addr(t, a2));
        float mx = v[0];
#pragma unroll
        for (int a2 = 1; a2 < 10; ++a2) mx = fmaxf(mx, v[a2]);
        float sum = 0.f;
#pragma unroll
        for (int a2 = 0; a2 < 10; ++a2) { v[a2] = __expf(v[a2] - mx); sum += v[a2]; }
        float inv = 1.0f / sum;
#pragma unroll
        for (int a2 = 0; a2 < 10; ++a2) *(float*)(smem + ps_addr(t, a2)) = v[a2] * inv;
    }
    __syncthreads();

    for (int o = t; o < 640; o += 256) {
        int n = o / 10, a2 = o - n * 10;
        out_policy[(size_t)b2 * 640 + o] = *(const float*)(smem + ps_addr(n, a2));
    }
}

}  // namespace

extern "C" void kernel_launch(void* const* d_in, const int* in_sizes, int n_in,
                              void* d_out, int out_size, void* d_ws, size_t ws_size,
                              hipStream_t stream) {
    const float* states = (const float*)d_in[0];
    const float* Wk1 = (const float*)d_in[1];
    const float* Wq1 = (const float*)d_in[2];
    const float* Wv1 = (const float*)d_in[3];
    const float* Wk2 = (const float*)d_in[4];
    const float* Wq2 = (const float*)d_in[5];
    const float* Wv2 = (const float*)d_in[6];
    const float* Wp1 = (const float*)d_in[7];
    const float* Wp2 = (const float*)d_in[8];

    const int B = in_sizes[0] / 4096;   // 8192 batches

    uint8_t* wsb = (uint8_t*)d_ws;      // needs ~541 KB
    float* out        = (float*)d_out;
    float* out_policy = out;
    float* out_w1     = out_policy + (size_t)B * 320;
    float* out_w2     = out_w1 + (size_t)B * 1024;

    hipLaunchKernelGGL(prepack, dim3(264), dim3(64), 0, stream,
                       Wk1, Wq1, Wv1, Wk2, Wq2, Wv2, Wp1, Wp2, wsb);
    hipLaunchKernelGGL(fused_net, dim3(B / 2), dim3(256), 0, stream,
                       states, wsb, out_policy, out_w1, out_w2);
}